// Round 5
// baseline (21289.877 us; speedup 1.0000x reference)
//
#include <hip/hip_runtime.h>
#include <hip/hip_bf16.h>

#define SEQ    256
#define BATCH  64
#define EMB    256
#define HID    1024
#define GATES  3072   // 3*HID
#define NCLS   128
#define TCH    16                 // time chunk
#define ROWS   (TCH * BATCH)      // 1024 rows per chunk

typedef __attribute__((ext_vector_type(8))) short bf16x8;
typedef __attribute__((ext_vector_type(4))) float f32x4;

__device__ inline unsigned short f2bf(float x) {
    union { float f; unsigned int u; } v; v.f = x;
    v.u += 0x7fffu + ((v.u >> 16) & 1u);   // RNE
    return (unsigned short)(v.u >> 16);
}

// ---------------------------------------------------------------------------
__global__ void conv_bf16(const float* __restrict__ in, unsigned short* __restrict__ out, int n) {
    int i = (blockIdx.x * 256 + threadIdx.x) * 4;
    if (i < n) {
        float4 v = *(const float4*)(in + i);
        out[i + 0] = f2bf(v.x); out[i + 1] = f2bf(v.y);
        out[i + 2] = f2bf(v.z); out[i + 3] = f2bf(v.w);
    }
}

// ---------------------------------------------------------------------------
// bf16 MFMA GEMM: C[M,N] = A[M,K] * Bw[N,K]^T + bias[N]  (unchanged, proven)
// ---------------------------------------------------------------------------
template <int MODE>
__global__ void gemm_mfma(const unsigned short* __restrict__ A,
                          const unsigned short* __restrict__ Bw,
                          const float* __restrict__ bias, float* __restrict__ Cout,
                          int N, int K, const int* __restrict__ xidx,
                          const unsigned short* __restrict__ emb, int row_base) {
    const int tid = threadIdx.x;
    const int w = tid >> 6, l = tid & 63;
    const int m0 = blockIdx.x * 64 + w * 16;
    const int n0 = blockIdx.y * 64;
    const int la = l & 15, lk = (l >> 4) * 8;

    const unsigned short* arow;
    if (MODE == 1) {
        int g = row_base + m0 + la;
        int s = g >> 6, b = g & 63;
        arow = emb + (size_t)xidx[b * SEQ + s] * K + lk;
    } else {
        arow = A + (size_t)(m0 + la) * K + lk;
    }
    const unsigned short* brow = Bw + (size_t)(n0 + la) * K + lk;

    f32x4 acc[4] = {};
    for (int k = 0; k < K; k += 32) {
        bf16x8 a = *(const bf16x8*)(arow + k);
#pragma unroll
        for (int nt = 0; nt < 4; ++nt) {
            bf16x8 bb = *(const bf16x8*)(brow + (size_t)nt * 16 * K + k);
            acc[nt] = __builtin_amdgcn_mfma_f32_16x16x32_bf16(a, bb, acc[nt], 0, 0, 0);
        }
    }

    const int rbase = (l >> 4) * 4;
#pragma unroll
    for (int nt = 0; nt < 4; ++nt) {
        int colg = n0 + nt * 16 + la;
        float bsv = bias[colg];
#pragma unroll
        for (int i = 0; i < 4; ++i) {
            int rowg = m0 + rbase + i;
            float v = acc[nt][i] + bsv;
            if (MODE == 2) {
                int g = row_base + rowg;
                int s = g >> 6, b = g & 63;
                Cout[((size_t)(b * SEQ + s)) * NCLS + colg] = v;
            } else {
                Cout[(size_t)rowg * N + colg] = v;
            }
        }
    }
}

// ---------------------------------------------------------------------------
// Persistent GRU chunk kernel (round-4 structure), with a DISTRIBUTED-FLAG
// barrier replacing the hot-counter barrier:
//   arrival: one release store to this block's own 64B-strided flag
//   wait:    wave 0 polls all 64 group flags with ONE 64-lane load / iter
// flags region per launch: 4 groups x 64 blocks x 16 ints (64 B apart).
// ---------------------------------------------------------------------------
__global__ __launch_bounds__(256, 1)
void gru_chunk(const float* __restrict__ gi,
               const unsigned short* __restrict__ whb,   // [3072][1024] bf16
               const float* __restrict__ b_hh,
               float* __restrict__ h_f,                  // [64][1024] f32 persistent
               unsigned short* __restrict__ hb0,         // ping (entry state)
               unsigned short* __restrict__ hb1,         // pong
               unsigned short* __restrict__ outseq,      // [TCH*64][1024] bf16
               int* __restrict__ bar) {                  // this launch's flag region
    extern __shared__ char smem[];
    float* sg = (float*)(smem + 3 * 16 * HID * 2);            // 3*256 f32

    const int bg = blockIdx.x >> 6;
    const int jt = blockIdx.x & 63;
    const int b0 = bg * 16, j0 = jt * 16;
    const int tid = threadIdx.x;
    const int w = tid >> 6, l = tid & 63;

    // ---- stage w slice into LDS (once), swizzled: byte ^= (row&7)<<4 ----
#pragma unroll
    for (int c = 0; c < 24; ++c) {
        int u = tid + 256 * c;            // 16B-unit id, 0..6143
        int row = u >> 7;                 // 0..47  (g*16 + r)
        int off16 = u & 127;              // 16B offset within row
        int g = row >> 4, r = row & 15;
        const unsigned short* src = whb + (size_t)(g * HID + j0 + r) * HID + off16 * 8;
        int byte = row * 2048 + ((off16 * 16) ^ ((r & 7) << 4));
        *(bf16x8*)(smem + byte) = *(const bf16x8*)src;
    }

    // ---- own f32 state + biases ----
    const int prow = tid >> 4, pcol = tid & 15;
    const int pb = b0 + prow, pj = j0 + pcol;
    float hp = h_f[(size_t)pb * HID + pj];
    const float bhr = b_hh[pj], bhz = b_hh[HID + pj], bhn = b_hh[2 * HID + pj];

    __syncthreads();

    const unsigned short* hbuf[2] = {hb0, hb1};

    for (int t = 0; t < TCH; ++t) {
        const unsigned short* hin = hbuf[t & 1];
        unsigned short* hout = (unsigned short*)hbuf[(t + 1) & 1];

        if (w < 3) {
            f32x4 acc = {};
            const int r = l & 15;
            const unsigned short* hrow = hin + (size_t)(b0 + r) * HID + ((l >> 4) * 8);
            const int rowbyte = (w * 16 + r) * 2048;
            const int sw = (r & 7) << 4;
            const int kq = (l >> 4) * 16;
#pragma unroll
            for (int ks = 0; ks < 32; ++ks) {
                bf16x8 a = *(const bf16x8*)(hrow + ks * 32);
                bf16x8 b = *(const bf16x8*)(smem + rowbyte + ((ks * 64 + kq) ^ sw));
                acc = __builtin_amdgcn_mfma_f32_16x16x32_bf16(a, b, acc, 0, 0, 0);
            }
            const int col = l & 15, rbase = (l >> 4) * 4;
#pragma unroll
            for (int i = 0; i < 4; ++i) sg[w * 256 + (rbase + i) * 16 + col] = acc[i];
        }
        __syncthreads();

        // ---- pointwise (all 256 threads, own (b,j)) ----
        const float* git = gi + ((size_t)(t * BATCH + pb)) * GATES;
        float ghr = sg[0 * 256 + tid] + bhr;
        float ghz = sg[1 * 256 + tid] + bhz;
        float ghn = sg[2 * 256 + tid] + bhn;
        float rr = 1.f / (1.f + __expf(-(git[pj] + ghr)));
        float zz = 1.f / (1.f + __expf(-(git[HID + pj] + ghz)));
        float nn = tanhf(git[2 * HID + pj] + rr * ghn);
        hp = (1.f - zz) * nn + zz * hp;
        unsigned short hb = f2bf(hp);
        hout[(size_t)pb * HID + pj] = hb;
        outseq[((size_t)(t * BATCH + pb)) * HID + pj] = hb;

        if (t < TCH - 1) {
            // ---- distributed-flag barrier over the 64 blocks of group bg ----
            __syncthreads();          // all h stores issued
            __threadfence();          // release own writes to device scope
            if (tid == 0) {
                __hip_atomic_store(bar + (((bg << 6) | jt) << 4), t + 1,
                                   __ATOMIC_RELEASE, __HIP_MEMORY_SCOPE_AGENT);
            }
            if (tid < 64) {
                const int* f = bar + (((bg << 6) | tid) << 4);
                while (!__all(__hip_atomic_load(f, __ATOMIC_RELAXED,
                                                __HIP_MEMORY_SCOPE_AGENT) > t)) {
                    __builtin_amdgcn_s_sleep(1);
                }
            }
            __syncthreads();
            __threadfence();          // acquire: subsequent h reads see remote writes
        }
    }

    h_f[(size_t)pb * HID + pj] = hp;
}

// ---------------------------------------------------------------------------
extern "C" void kernel_launch(void* const* d_in, const int* in_sizes, int n_in,
                              void* d_out, int out_size, void* d_ws, size_t ws_size,
                              hipStream_t stream) {
    const int*   x      = (const int*)d_in[0];
    const float* hs     = (const float*)d_in[1];
    const float* emb    = (const float*)d_in[2];
    const float* w_ih0  = (const float*)d_in[3];
    const float* w_hh0  = (const float*)d_in[4];
    const float* b_ih0  = (const float*)d_in[5];
    const float* b_hh0  = (const float*)d_in[6];
    const float* w_ih1  = (const float*)d_in[7];
    const float* w_hh1  = (const float*)d_in[8];
    const float* b_ih1  = (const float*)d_in[9];
    const float* b_hh1  = (const float*)d_in[10];
    const float* w_proj = (const float*)d_in[11];
    const float* b_proj = (const float*)d_in[12];

    float* logits = (float*)d_out;                       // [B*S, 128] f32
    float* hT     = logits + (size_t)SEQ * BATCH * NCLS; // [2, 64, 1024] f32

    // ---- workspace layout ----
    char* p = (char*)d_ws;
    float* gi = (float*)p;                      p += (size_t)ROWS * GATES * 4;   // 12.6 MB
    float* h0f = (float*)p;                     p += 65536 * 4;
    float* h1f = (float*)p;                     p += 65536 * 4;
    unsigned short* h0b0 = (unsigned short*)p;  p += 65536 * 2;
    unsigned short* h0b1 = (unsigned short*)p;  p += 65536 * 2;
    unsigned short* h1b0 = (unsigned short*)p;  p += 65536 * 2;
    unsigned short* h1b1 = (unsigned short*)p;  p += 65536 * 2;
    unsigned short* out0b = (unsigned short*)p; p += (size_t)ROWS * HID * 2;     // 2.1 MB
    unsigned short* out1b = (unsigned short*)p; p += (size_t)ROWS * HID * 2;     // 2.1 MB
    unsigned short* embB  = (unsigned short*)p; p += (size_t)NCLS * EMB * 2;
    unsigned short* wih0B = (unsigned short*)p; p += (size_t)GATES * EMB * 2;
    unsigned short* whh0B = (unsigned short*)p; p += (size_t)GATES * HID * 2;
    unsigned short* wih1B = (unsigned short*)p; p += (size_t)GATES * HID * 2;
    unsigned short* whh1B = (unsigned short*)p; p += (size_t)GATES * HID * 2;
    unsigned short* wprojB = (unsigned short*)p; p += (size_t)NCLS * HID * 2;
    int* bar = (int*)p;                         p += (size_t)32 * 4096 * 4;      // 512 KB flags

    // allow >64KB dynamic LDS for the persistent kernel
    hipFuncSetAttribute((const void*)gru_chunk,
                        hipFuncAttributeMaxDynamicSharedMemorySize, 112 * 1024);
    const int GRU_LDS = 3 * 16 * HID * 2 + 3 * 256 * 4;   // 98304 + 3072

    // ---- flag regions: reset every call (graph-replay safe) ----
    hipMemsetAsync(bar, 0, (size_t)32 * 4096 * 4, stream);

    // ---- one-time weight conversions ----
    conv_bf16<<<(NCLS * EMB) / 1024, 256, 0, stream>>>(emb, embB, NCLS * EMB);
    conv_bf16<<<(GATES * EMB) / 1024, 256, 0, stream>>>(w_ih0, wih0B, GATES * EMB);
    conv_bf16<<<(GATES * HID) / 1024, 256, 0, stream>>>(w_hh0, whh0B, GATES * HID);
    conv_bf16<<<(GATES * HID) / 1024, 256, 0, stream>>>(w_ih1, wih1B, GATES * HID);
    conv_bf16<<<(GATES * HID) / 1024, 256, 0, stream>>>(w_hh1, whh1B, GATES * HID);
    conv_bf16<<<(NCLS * HID) / 1024, 256, 0, stream>>>(w_proj, wprojB, NCLS * HID);

    // ---- init hidden state ----
    hipMemcpyAsync(h0f, hs, 65536 * 4, hipMemcpyDeviceToDevice, stream);
    hipMemcpyAsync(h1f, hs + 65536, 65536 * 4, hipMemcpyDeviceToDevice, stream);
    conv_bf16<<<64, 256, 0, stream>>>(hs, h0b0, 65536);
    conv_bf16<<<64, 256, 0, stream>>>(hs + 65536, h1b0, 65536);

    dim3 gg(ROWS / 64, GATES / 64);   // (16, 48)
    dim3 gp(ROWS / 64, NCLS / 64);    // (16, 2)

    for (int c = 0; c < SEQ / TCH; ++c) {
        int row_base = c * ROWS;

        // gi = embed[x] @ w_ih0^T + b_ih0 (gathered A)
        gemm_mfma<1><<<gg, 256, 0, stream>>>(nullptr, wih0B, b_ih0, gi, GATES, EMB, x, embB, row_base);

        // layer 0: 16 steps, one persistent launch
        gru_chunk<<<256, 256, GRU_LDS, stream>>>(gi, whh0B, b_hh0, h0f, h0b0, h0b1,
                                                 out0b, bar + (size_t)(c * 2 + 0) * 4096);

        // gi = out0 @ w_ih1^T + b_ih1
        gemm_mfma<0><<<gg, 256, 0, stream>>>(out0b, wih1B, b_ih1, gi, GATES, HID, nullptr, nullptr, 0);

        // layer 1: 16 steps, one persistent launch
        gru_chunk<<<256, 256, GRU_LDS, stream>>>(gi, whh1B, b_hh1, h1f, h1b0, h1b1,
                                                 out1b, bar + (size_t)(c * 2 + 1) * 4096);

        // logits chunk = out1 @ w_proj^T + b_proj (remapped store)
        gemm_mfma<2><<<gp, 256, 0, stream>>>(out1b, wprojB, b_proj, logits, NCLS, HID, nullptr, nullptr, row_base);
    }

    hipMemcpyAsync(hT, h0f, 65536 * 4, hipMemcpyDeviceToDevice, stream);
    hipMemcpyAsync(hT + 65536, h1f, 65536 * 4, hipMemcpyDeviceToDevice, stream);
}

// Round 6
// 4506.240 us; speedup vs baseline: 4.7245x; 4.7245x over previous
//
#include <hip/hip_runtime.h>
#include <hip/hip_bf16.h>

#define SEQ    256
#define BATCH  64
#define EMB    256
#define HID    1024
#define GATES  3072   // 3*HID
#define NCLS   128
#define TCH    16                 // time chunk
#define ROWS   (TCH * BATCH)      // 1024 rows per chunk

typedef __attribute__((ext_vector_type(8))) short bf16x8;
typedef __attribute__((ext_vector_type(4))) float f32x4;

__device__ inline unsigned short f2bf(float x) {
    union { float f; unsigned int u; } v; v.f = x;
    v.u += 0x7fffu + ((v.u >> 16) & 1u);   // RNE
    return (unsigned short)(v.u >> 16);
}

// ---------------------------------------------------------------------------
__global__ void conv_bf16(const float* __restrict__ in, unsigned short* __restrict__ out, int n) {
    int i = (blockIdx.x * 256 + threadIdx.x) * 4;
    if (i < n) {
        float4 v = *(const float4*)(in + i);
        out[i + 0] = f2bf(v.x); out[i + 1] = f2bf(v.y);
        out[i + 2] = f2bf(v.z); out[i + 3] = f2bf(v.w);
    }
}

// ---------------------------------------------------------------------------
// bf16 MFMA GEMM: C[M,N] = A[M,K] * Bw[N,K]^T + bias[N]  (unchanged, proven)
// ---------------------------------------------------------------------------
template <int MODE>
__global__ void gemm_mfma(const unsigned short* __restrict__ A,
                          const unsigned short* __restrict__ Bw,
                          const float* __restrict__ bias, float* __restrict__ Cout,
                          int N, int K, const int* __restrict__ xidx,
                          const unsigned short* __restrict__ emb, int row_base) {
    const int tid = threadIdx.x;
    const int w = tid >> 6, l = tid & 63;
    const int m0 = blockIdx.x * 64 + w * 16;
    const int n0 = blockIdx.y * 64;
    const int la = l & 15, lk = (l >> 4) * 8;

    const unsigned short* arow;
    if (MODE == 1) {
        int g = row_base + m0 + la;
        int s = g >> 6, b = g & 63;
        arow = emb + (size_t)xidx[b * SEQ + s] * K + lk;
    } else {
        arow = A + (size_t)(m0 + la) * K + lk;
    }
    const unsigned short* brow = Bw + (size_t)(n0 + la) * K + lk;

    f32x4 acc[4] = {};
    for (int k = 0; k < K; k += 32) {
        bf16x8 a = *(const bf16x8*)(arow + k);
#pragma unroll
        for (int nt = 0; nt < 4; ++nt) {
            bf16x8 bb = *(const bf16x8*)(brow + (size_t)nt * 16 * K + k);
            acc[nt] = __builtin_amdgcn_mfma_f32_16x16x32_bf16(a, bb, acc[nt], 0, 0, 0);
        }
    }

    const int rbase = (l >> 4) * 4;
#pragma unroll
    for (int nt = 0; nt < 4; ++nt) {
        int colg = n0 + nt * 16 + la;
        float bsv = bias[colg];
#pragma unroll
        for (int i = 0; i < 4; ++i) {
            int rowg = m0 + rbase + i;
            float v = acc[nt][i] + bsv;
            if (MODE == 2) {
                int g = row_base + rowg;
                int s = g >> 6, b = g & 63;
                Cout[((size_t)(b * SEQ + s)) * NCLS + colg] = v;
            } else {
                Cout[(size_t)rowg * N + colg] = v;
            }
        }
    }
}

// ---------------------------------------------------------------------------
// issue 8 coherence-point (sc0 sc1) 16B loads from base, offsets 0..448 B
// ---------------------------------------------------------------------------
#define LD8(B, POFF)                                                          \
    asm volatile(                                                             \
        "global_load_dwordx4 %0, %8, off sc0 sc1\n\t"                         \
        "global_load_dwordx4 %1, %8, off offset:64 sc0 sc1\n\t"               \
        "global_load_dwordx4 %2, %8, off offset:128 sc0 sc1\n\t"              \
        "global_load_dwordx4 %3, %8, off offset:192 sc0 sc1\n\t"              \
        "global_load_dwordx4 %4, %8, off offset:256 sc0 sc1\n\t"              \
        "global_load_dwordx4 %5, %8, off offset:320 sc0 sc1\n\t"              \
        "global_load_dwordx4 %6, %8, off offset:384 sc0 sc1\n\t"              \
        "global_load_dwordx4 %7, %8, off offset:448 sc0 sc1"                  \
        : "=&v"(hf[(B) + 0]), "=&v"(hf[(B) + 1]), "=&v"(hf[(B) + 2]),         \
          "=&v"(hf[(B) + 3]), "=&v"(hf[(B) + 4]), "=&v"(hf[(B) + 5]),         \
          "=&v"(hf[(B) + 6]), "=&v"(hf[(B) + 7])                              \
        : "v"(hrow + (POFF)))

// ---------------------------------------------------------------------------
// Persistent GRU chunk kernel — FENCE-FREE cross-block h exchange.
// h stores/loads go to the coherence point (sc0 sc1), so no L2
// writeback/invalidate (threadfence) is ever needed inside the loop.
// Distributed per-block flags (64B-strided), relaxed atomics only.
// ---------------------------------------------------------------------------
__global__ __launch_bounds__(256, 1)
void gru_chunk(const float* __restrict__ gi,
               const unsigned short* __restrict__ whb,   // [3072][1024] bf16
               const float* __restrict__ b_hh,
               float* __restrict__ h_f,                  // [64][1024] f32 persistent
               unsigned short* __restrict__ hb0,         // ping (entry state)
               unsigned short* __restrict__ hb1,         // pong
               unsigned short* __restrict__ outseq,      // [TCH*64][1024] bf16
               int* __restrict__ bar) {                  // this launch's flag region
    extern __shared__ char smem[];
    float* sg = (float*)(smem + 3 * 16 * HID * 2);            // 3*256 f32

    const int bg = blockIdx.x >> 6;
    const int jt = blockIdx.x & 63;
    const int b0 = bg * 16, j0 = jt * 16;
    const int tid = threadIdx.x;
    const int w = tid >> 6, l = tid & 63;

    // ---- stage w slice into LDS (once), swizzled: byte ^= (row&7)<<4 ----
#pragma unroll
    for (int c = 0; c < 24; ++c) {
        int u = tid + 256 * c;            // 16B-unit id, 0..6143
        int row = u >> 7;                 // 0..47  (g*16 + r)
        int off16 = u & 127;              // 16B offset within row
        int g = row >> 4, r = row & 15;
        const unsigned short* src = whb + (size_t)(g * HID + j0 + r) * HID + off16 * 8;
        int byte = row * 2048 + ((off16 * 16) ^ ((r & 7) << 4));
        *(bf16x8*)(smem + byte) = *(const bf16x8*)src;
    }

    // ---- own f32 state + biases ----
    const int prow = tid >> 4, pcol = tid & 15;
    const int pb = b0 + prow, pj = j0 + pcol;
    float hp = h_f[(size_t)pb * HID + pj];
    const float bhr = b_hh[pj], bhz = b_hh[HID + pj], bhn = b_hh[2 * HID + pj];

    __syncthreads();

    const unsigned short* hbuf[2] = {hb0, hb1};

    for (int t = 0; t < TCH; ++t) {
        const unsigned short* hin = hbuf[t & 1];
        unsigned short* hout = (unsigned short*)hbuf[(t + 1) & 1];

        if (w < 3) {
            const int r = l & 15;
            const unsigned short* hrow = hin + (size_t)(b0 + r) * HID + ((l >> 4) * 8);
            bf16x8 hf[32];
            LD8(0, 0);
            LD8(8, 256);
            LD8(16, 512);
            LD8(24, 768);
            asm volatile("s_waitcnt vmcnt(0)" ::: "memory");
            __builtin_amdgcn_sched_barrier(0);

            f32x4 acc = {};
            const int rowbyte = (w * 16 + r) * 2048;
            const int sw = (r & 7) << 4;
            const int kq = (l >> 4) * 16;
#pragma unroll
            for (int ks = 0; ks < 32; ++ks) {
                bf16x8 b = *(const bf16x8*)(smem + rowbyte + ((ks * 64 + kq) ^ sw));
                acc = __builtin_amdgcn_mfma_f32_16x16x32_bf16(hf[ks], b, acc, 0, 0, 0);
            }
            const int col = l & 15, rbase = (l >> 4) * 4;
#pragma unroll
            for (int i = 0; i < 4; ++i) sg[w * 256 + (rbase + i) * 16 + col] = acc[i];
        }
        __syncthreads();

        // ---- pointwise (all 256 threads, own (b,j)) ----
        const float* git = gi + ((size_t)(t * BATCH + pb)) * GATES;
        float ghr = sg[0 * 256 + tid] + bhr;
        float ghz = sg[1 * 256 + tid] + bhz;
        float ghn = sg[2 * 256 + tid] + bhn;
        float rr = 1.f / (1.f + __expf(-(git[pj] + ghr)));
        float zz = 1.f / (1.f + __expf(-(git[HID + pj] + ghz)));
        float nn = tanhf(git[2 * HID + pj] + rr * ghn);
        hp = (1.f - zz) * nn + zz * hp;
        unsigned short hb = f2bf(hp);
        outseq[((size_t)(t * BATCH + pb)) * HID + pj] = hb;

        // coherence-point store of own h + per-wave drain (asm stores are
        // invisible to the compiler's pre-barrier waitcnt, so drain here)
        asm volatile(
            "global_store_short %0, %1, off sc0 sc1\n\t"
            "s_waitcnt vmcnt(0)"
            :: "v"(hout + (size_t)pb * HID + pj), "v"((unsigned int)hb)
            : "memory");

        if (t < TCH - 1) {
            // ---- distributed-flag barrier over the 64 blocks of group bg ----
            __syncthreads();          // every wave's h store drained above
            if (tid == 0) {
                __hip_atomic_store(bar + (((bg << 6) | jt) << 4), t + 1,
                                   __ATOMIC_RELAXED, __HIP_MEMORY_SCOPE_AGENT);
            }
            if (tid < 64) {
                const int* f = bar + (((bg << 6) | tid) << 4);
                while (!__all(__hip_atomic_load(f, __ATOMIC_RELAXED,
                                                __HIP_MEMORY_SCOPE_AGENT) > t)) {
                    __builtin_amdgcn_s_sleep(1);
                }
            }
            __syncthreads();
        }
    }

    h_f[(size_t)pb * HID + pj] = hp;
}

// ---------------------------------------------------------------------------
extern "C" void kernel_launch(void* const* d_in, const int* in_sizes, int n_in,
                              void* d_out, int out_size, void* d_ws, size_t ws_size,
                              hipStream_t stream) {
    const int*   x      = (const int*)d_in[0];
    const float* hs     = (const float*)d_in[1];
    const float* emb    = (const float*)d_in[2];
    const float* w_ih0  = (const float*)d_in[3];
    const float* w_hh0  = (const float*)d_in[4];
    const float* b_ih0  = (const float*)d_in[5];
    const float* b_hh0  = (const float*)d_in[6];
    const float* w_ih1  = (const float*)d_in[7];
    const float* w_hh1  = (const float*)d_in[8];
    const float* b_ih1  = (const float*)d_in[9];
    const float* b_hh1  = (const float*)d_in[10];
    const float* w_proj = (const float*)d_in[11];
    const float* b_proj = (const float*)d_in[12];

    float* logits = (float*)d_out;                       // [B*S, 128] f32
    float* hT     = logits + (size_t)SEQ * BATCH * NCLS; // [2, 64, 1024] f32

    // ---- workspace layout ----
    char* p = (char*)d_ws;
    float* gi = (float*)p;                      p += (size_t)ROWS * GATES * 4;   // 12.6 MB
    float* h0f = (float*)p;                     p += 65536 * 4;
    float* h1f = (float*)p;                     p += 65536 * 4;
    unsigned short* h0b0 = (unsigned short*)p;  p += 65536 * 2;
    unsigned short* h0b1 = (unsigned short*)p;  p += 65536 * 2;
    unsigned short* h1b0 = (unsigned short*)p;  p += 65536 * 2;
    unsigned short* h1b1 = (unsigned short*)p;  p += 65536 * 2;
    unsigned short* out0b = (unsigned short*)p; p += (size_t)ROWS * HID * 2;     // 2.1 MB
    unsigned short* out1b = (unsigned short*)p; p += (size_t)ROWS * HID * 2;     // 2.1 MB
    unsigned short* embB  = (unsigned short*)p; p += (size_t)NCLS * EMB * 2;
    unsigned short* wih0B = (unsigned short*)p; p += (size_t)GATES * EMB * 2;
    unsigned short* whh0B = (unsigned short*)p; p += (size_t)GATES * HID * 2;
    unsigned short* wih1B = (unsigned short*)p; p += (size_t)GATES * HID * 2;
    unsigned short* whh1B = (unsigned short*)p; p += (size_t)GATES * HID * 2;
    unsigned short* wprojB = (unsigned short*)p; p += (size_t)NCLS * HID * 2;
    int* bar = (int*)p;                         p += (size_t)32 * 4096 * 4;      // 512 KB flags

    // allow >64KB dynamic LDS for the persistent kernel
    hipFuncSetAttribute((const void*)gru_chunk,
                        hipFuncAttributeMaxDynamicSharedMemorySize, 112 * 1024);
    const int GRU_LDS = 3 * 16 * HID * 2 + 3 * 256 * 4;   // 98304 + 3072

    // ---- flag regions: reset every call (graph-replay safe) ----
    hipMemsetAsync(bar, 0, (size_t)32 * 4096 * 4, stream);

    // ---- one-time weight conversions ----
    conv_bf16<<<(NCLS * EMB) / 1024, 256, 0, stream>>>(emb, embB, NCLS * EMB);
    conv_bf16<<<(GATES * EMB) / 1024, 256, 0, stream>>>(w_ih0, wih0B, GATES * EMB);
    conv_bf16<<<(GATES * HID) / 1024, 256, 0, stream>>>(w_hh0, whh0B, GATES * HID);
    conv_bf16<<<(GATES * HID) / 1024, 256, 0, stream>>>(w_ih1, wih1B, GATES * HID);
    conv_bf16<<<(GATES * HID) / 1024, 256, 0, stream>>>(w_hh1, whh1B, GATES * HID);
    conv_bf16<<<(NCLS * HID) / 1024, 256, 0, stream>>>(w_proj, wprojB, NCLS * HID);

    // ---- init hidden state ----
    hipMemcpyAsync(h0f, hs, 65536 * 4, hipMemcpyDeviceToDevice, stream);
    hipMemcpyAsync(h1f, hs + 65536, 65536 * 4, hipMemcpyDeviceToDevice, stream);
    conv_bf16<<<64, 256, 0, stream>>>(hs, h0b0, 65536);
    conv_bf16<<<64, 256, 0, stream>>>(hs + 65536, h1b0, 65536);

    dim3 gg(ROWS / 64, GATES / 64);   // (16, 48)
    dim3 gp(ROWS / 64, NCLS / 64);    // (16, 2)

    for (int c = 0; c < SEQ / TCH; ++c) {
        int row_base = c * ROWS;

        // gi = embed[x] @ w_ih0^T + b_ih0 (gathered A)
        gemm_mfma<1><<<gg, 256, 0, stream>>>(nullptr, wih0B, b_ih0, gi, GATES, EMB, x, embB, row_base);

        // layer 0: 16 steps, one persistent launch
        gru_chunk<<<256, 256, GRU_LDS, stream>>>(gi, whh0B, b_hh0, h0f, h0b0, h0b1,
                                                 out0b, bar + (size_t)(c * 2 + 0) * 4096);

        // gi = out0 @ w_ih1^T + b_ih1
        gemm_mfma<0><<<gg, 256, 0, stream>>>(out0b, wih1B, b_ih1, gi, GATES, HID, nullptr, nullptr, 0);

        // layer 1: 16 steps, one persistent launch
        gru_chunk<<<256, 256, GRU_LDS, stream>>>(gi, whh1B, b_hh1, h1f, h1b0, h1b1,
                                                 out1b, bar + (size_t)(c * 2 + 1) * 4096);

        // logits chunk = out1 @ w_proj^T + b_proj (remapped store)
        gemm_mfma<2><<<gp, 256, 0, stream>>>(out1b, wprojB, b_proj, logits, NCLS, HID, nullptr, nullptr, row_base);
    }

    hipMemcpyAsync(hT, h0f, 65536 * 4, hipMemcpyDeviceToDevice, stream);
    hipMemcpyAsync(hT + 65536, h1f, 65536 * 4, hipMemcpyDeviceToDevice, stream);
}

// Round 7
// 3566.459 us; speedup vs baseline: 5.9695x; 1.2635x over previous
//
#include <hip/hip_runtime.h>
#include <hip/hip_bf16.h>

#define SEQ    256
#define BATCH  64
#define EMB    256
#define HID    1024
#define GATES  3072   // 3*HID
#define NCLS   128
#define TCH    16                 // time chunk
#define ROWS   (TCH * BATCH)      // 1024 rows per chunk

#define HOFF   101376             // LDS byte offset of h tile (96K w + 3K sg)

typedef __attribute__((ext_vector_type(8))) short bf16x8;
typedef __attribute__((ext_vector_type(4))) float f32x4;

__device__ inline unsigned short f2bf(float x) {
    union { float f; unsigned int u; } v; v.f = x;
    v.u += 0x7fffu + ((v.u >> 16) & 1u);   // RNE
    return (unsigned short)(v.u >> 16);
}

// ---------------------------------------------------------------------------
__global__ void conv_bf16(const float* __restrict__ in, unsigned short* __restrict__ out, int n) {
    int i = (blockIdx.x * 256 + threadIdx.x) * 4;
    if (i < n) {
        float4 v = *(const float4*)(in + i);
        out[i + 0] = f2bf(v.x); out[i + 1] = f2bf(v.y);
        out[i + 2] = f2bf(v.z); out[i + 3] = f2bf(v.w);
    }
}

// ---------------------------------------------------------------------------
// bf16 MFMA GEMM: C[M,N] = A[M,K] * Bw[N,K]^T + bias[N]  (unchanged, proven)
// ---------------------------------------------------------------------------
template <int MODE>
__global__ void gemm_mfma(const unsigned short* __restrict__ A,
                          const unsigned short* __restrict__ Bw,
                          const float* __restrict__ bias, float* __restrict__ Cout,
                          int N, int K, const int* __restrict__ xidx,
                          const unsigned short* __restrict__ emb, int row_base) {
    const int tid = threadIdx.x;
    const int w = tid >> 6, l = tid & 63;
    const int m0 = blockIdx.x * 64 + w * 16;
    const int n0 = blockIdx.y * 64;
    const int la = l & 15, lk = (l >> 4) * 8;

    const unsigned short* arow;
    if (MODE == 1) {
        int g = row_base + m0 + la;
        int s = g >> 6, b = g & 63;
        arow = emb + (size_t)xidx[b * SEQ + s] * K + lk;
    } else {
        arow = A + (size_t)(m0 + la) * K + lk;
    }
    const unsigned short* brow = Bw + (size_t)(n0 + la) * K + lk;

    f32x4 acc[4] = {};
    for (int k = 0; k < K; k += 32) {
        bf16x8 a = *(const bf16x8*)(arow + k);
#pragma unroll
        for (int nt = 0; nt < 4; ++nt) {
            bf16x8 bb = *(const bf16x8*)(brow + (size_t)nt * 16 * K + k);
            acc[nt] = __builtin_amdgcn_mfma_f32_16x16x32_bf16(a, bb, acc[nt], 0, 0, 0);
        }
    }

    const int rbase = (l >> 4) * 4;
#pragma unroll
    for (int nt = 0; nt < 4; ++nt) {
        int colg = n0 + nt * 16 + la;
        float bsv = bias[colg];
#pragma unroll
        for (int i = 0; i < 4; ++i) {
            int rowg = m0 + rbase + i;
            float v = acc[nt][i] + bsv;
            if (MODE == 2) {
                int g = row_base + rowg;
                int s = g >> 6, b = g & 63;
                Cout[((size_t)(b * SEQ + s)) * NCLS + colg] = v;
            } else {
                Cout[(size_t)rowg * N + colg] = v;
            }
        }
    }
}

// ---------------------------------------------------------------------------
// Persistent GRU chunk kernel — fence-free h exchange (sc0 sc1), with h
// staged into LDS ONCE per step by all 4 waves (3x coherence-traffic cut).
// ---------------------------------------------------------------------------
__global__ __launch_bounds__(256, 1)
void gru_chunk(const float* __restrict__ gi,
               const unsigned short* __restrict__ whb,   // [3072][1024] bf16
               const float* __restrict__ b_hh,
               float* __restrict__ h_f,                  // [64][1024] f32 persistent
               unsigned short* __restrict__ hb0,         // ping (entry state)
               unsigned short* __restrict__ hb1,         // pong
               unsigned short* __restrict__ outseq,      // [TCH*64][1024] bf16
               int* __restrict__ bar) {                  // this launch's flag region
    extern __shared__ char smem[];
    float* sg = (float*)(smem + 3 * 16 * HID * 2);            // 3*256 f32 @ 96K

    const int bg = blockIdx.x >> 6;
    const int jt = blockIdx.x & 63;
    const int b0 = bg * 16, j0 = jt * 16;
    const int tid = threadIdx.x;
    const int w = tid >> 6, l = tid & 63;

    // ---- stage w slice into LDS (once), swizzled: byte ^= (row&7)<<4 ----
#pragma unroll
    for (int c = 0; c < 24; ++c) {
        int u = tid + 256 * c;            // 16B-unit id, 0..6143
        int row = u >> 7;                 // 0..47  (g*16 + r)
        int off16 = u & 127;              // 16B offset within row
        int g = row >> 4, r = row & 15;
        const unsigned short* src = whb + (size_t)(g * HID + j0 + r) * HID + off16 * 8;
        int byte = row * 2048 + ((off16 * 16) ^ ((r & 7) << 4));
        *(bf16x8*)(smem + byte) = *(const bf16x8*)src;
    }

    // ---- own f32 state + biases ----
    const int prow = tid >> 4, pcol = tid & 15;
    const int pb = b0 + prow, pj = j0 + pcol;
    float hp = h_f[(size_t)pb * HID + pj];
    const float bhr = b_hh[pj], bhz = b_hh[HID + pj], bhn = b_hh[2 * HID + pj];

    __syncthreads();

    const unsigned short* hbuf[2] = {hb0, hb1};
    const int thi = tid >> 7;           // 0/1: which of the pair of rows
    const int tlo = tid & 127;          // 16B-unit within row

    for (int t = 0; t < TCH; ++t) {
        const unsigned short* hin = hbuf[t & 1];
        unsigned short* hout = (unsigned short*)hbuf[(t + 1) & 1];

        // ---- cooperative h-tile stage: 16 rows x 1024 bf16 = 32 KB ----
        // unit u = tid + 256*c  ->  row = 2c + thi, off16 = tlo
        bf16x8 h0v, h1v, h2v, h3v, h4v, h5v, h6v, h7v;
        {
            const unsigned short* s0 = hin + (size_t)(b0 + 2 * 0 + thi) * HID + tlo * 8;
            const unsigned short* s1 = hin + (size_t)(b0 + 2 * 1 + thi) * HID + tlo * 8;
            const unsigned short* s2 = hin + (size_t)(b0 + 2 * 2 + thi) * HID + tlo * 8;
            const unsigned short* s3 = hin + (size_t)(b0 + 2 * 3 + thi) * HID + tlo * 8;
            const unsigned short* s4 = hin + (size_t)(b0 + 2 * 4 + thi) * HID + tlo * 8;
            const unsigned short* s5 = hin + (size_t)(b0 + 2 * 5 + thi) * HID + tlo * 8;
            const unsigned short* s6 = hin + (size_t)(b0 + 2 * 6 + thi) * HID + tlo * 8;
            const unsigned short* s7 = hin + (size_t)(b0 + 2 * 7 + thi) * HID + tlo * 8;
            asm volatile(
                "global_load_dwordx4 %0, %8, off sc0 sc1\n\t"
                "global_load_dwordx4 %1, %9, off sc0 sc1\n\t"
                "global_load_dwordx4 %2, %10, off sc0 sc1\n\t"
                "global_load_dwordx4 %3, %11, off sc0 sc1\n\t"
                "global_load_dwordx4 %4, %12, off sc0 sc1\n\t"
                "global_load_dwordx4 %5, %13, off sc0 sc1\n\t"
                "global_load_dwordx4 %6, %14, off sc0 sc1\n\t"
                "global_load_dwordx4 %7, %15, off sc0 sc1"
                : "=&v"(h0v), "=&v"(h1v), "=&v"(h2v), "=&v"(h3v),
                  "=&v"(h4v), "=&v"(h5v), "=&v"(h6v), "=&v"(h7v)
                : "v"(s0), "v"(s1), "v"(s2), "v"(s3),
                  "v"(s4), "v"(s5), "v"(s6), "v"(s7));
            asm volatile("s_waitcnt vmcnt(0)" ::: "memory");
            __builtin_amdgcn_sched_barrier(0);
        }
#define HDST(c) (bf16x8*)(smem + HOFF + (2 * (c) + thi) * 2048 + \
                          ((tlo * 16) ^ (((2 * (c) + thi) & 7) << 4)))
        *HDST(0) = h0v; *HDST(1) = h1v; *HDST(2) = h2v; *HDST(3) = h3v;
        *HDST(4) = h4v; *HDST(5) = h5v; *HDST(6) = h6v; *HDST(7) = h7v;
#undef HDST
        __syncthreads();

        if (w < 3) {
            const int r = l & 15;
            const int sw = (r & 7) << 4;
            const int kq = (l >> 4) * 16;
            const int hbyte = HOFF + r * 2048;
            const int rowbyte = (w * 16 + r) * 2048;
            f32x4 acc = {};
#pragma unroll
            for (int ks = 0; ks < 32; ++ks) {
                bf16x8 a = *(const bf16x8*)(smem + hbyte + ((ks * 64 + kq) ^ sw));
                bf16x8 b = *(const bf16x8*)(smem + rowbyte + ((ks * 64 + kq) ^ sw));
                acc = __builtin_amdgcn_mfma_f32_16x16x32_bf16(a, b, acc, 0, 0, 0);
            }
            const int col = l & 15, rbase = (l >> 4) * 4;
#pragma unroll
            for (int i = 0; i < 4; ++i) sg[w * 256 + (rbase + i) * 16 + col] = acc[i];
        }
        __syncthreads();

        // ---- pointwise (all 256 threads, own (b,j)) ----
        const float* git = gi + ((size_t)(t * BATCH + pb)) * GATES;
        float ghr = sg[0 * 256 + tid] + bhr;
        float ghz = sg[1 * 256 + tid] + bhz;
        float ghn = sg[2 * 256 + tid] + bhn;
        float rr = 1.f / (1.f + __expf(-(git[pj] + ghr)));
        float zz = 1.f / (1.f + __expf(-(git[HID + pj] + ghz)));
        float nn = tanhf(git[2 * HID + pj] + rr * ghn);
        hp = (1.f - zz) * nn + zz * hp;
        unsigned short hb = f2bf(hp);
        outseq[((size_t)(t * BATCH + pb)) * HID + pj] = hb;

        // coherence-point store of own h + per-wave drain
        asm volatile(
            "global_store_short %0, %1, off sc0 sc1\n\t"
            "s_waitcnt vmcnt(0)"
            :: "v"(hout + (size_t)pb * HID + pj), "v"((unsigned int)hb)
            : "memory");

        if (t < TCH - 1) {
            // ---- distributed-flag barrier over the 64 blocks of group bg ----
            __syncthreads();          // every wave's h store drained above
            if (tid == 0) {
                __hip_atomic_store(bar + (((bg << 6) | jt) << 4), t + 1,
                                   __ATOMIC_RELAXED, __HIP_MEMORY_SCOPE_AGENT);
            }
            if (tid < 64) {
                const int* f = bar + (((bg << 6) | tid) << 4);
                while (!__all(__hip_atomic_load(f, __ATOMIC_RELAXED,
                                                __HIP_MEMORY_SCOPE_AGENT) > t)) {
                    __builtin_amdgcn_s_sleep(1);
                }
            }
            __syncthreads();
        }
    }

    h_f[(size_t)pb * HID + pj] = hp;
}

// ---------------------------------------------------------------------------
extern "C" void kernel_launch(void* const* d_in, const int* in_sizes, int n_in,
                              void* d_out, int out_size, void* d_ws, size_t ws_size,
                              hipStream_t stream) {
    const int*   x      = (const int*)d_in[0];
    const float* hs     = (const float*)d_in[1];
    const float* emb    = (const float*)d_in[2];
    const float* w_ih0  = (const float*)d_in[3];
    const float* w_hh0  = (const float*)d_in[4];
    const float* b_ih0  = (const float*)d_in[5];
    const float* b_hh0  = (const float*)d_in[6];
    const float* w_ih1  = (const float*)d_in[7];
    const float* w_hh1  = (const float*)d_in[8];
    const float* b_ih1  = (const float*)d_in[9];
    const float* b_hh1  = (const float*)d_in[10];
    const float* w_proj = (const float*)d_in[11];
    const float* b_proj = (const float*)d_in[12];

    float* logits = (float*)d_out;                       // [B*S, 128] f32
    float* hT     = logits + (size_t)SEQ * BATCH * NCLS; // [2, 64, 1024] f32

    // ---- workspace layout ----
    char* p = (char*)d_ws;
    float* gi = (float*)p;                      p += (size_t)ROWS * GATES * 4;   // 12.6 MB
    float* h0f = (float*)p;                     p += 65536 * 4;
    float* h1f = (float*)p;                     p += 65536 * 4;
    unsigned short* h0b0 = (unsigned short*)p;  p += 65536 * 2;
    unsigned short* h0b1 = (unsigned short*)p;  p += 65536 * 2;
    unsigned short* h1b0 = (unsigned short*)p;  p += 65536 * 2;
    unsigned short* h1b1 = (unsigned short*)p;  p += 65536 * 2;
    unsigned short* out0b = (unsigned short*)p; p += (size_t)ROWS * HID * 2;     // 2.1 MB
    unsigned short* out1b = (unsigned short*)p; p += (size_t)ROWS * HID * 2;     // 2.1 MB
    unsigned short* embB  = (unsigned short*)p; p += (size_t)NCLS * EMB * 2;
    unsigned short* wih0B = (unsigned short*)p; p += (size_t)GATES * EMB * 2;
    unsigned short* whh0B = (unsigned short*)p; p += (size_t)GATES * HID * 2;
    unsigned short* wih1B = (unsigned short*)p; p += (size_t)GATES * HID * 2;
    unsigned short* whh1B = (unsigned short*)p; p += (size_t)GATES * HID * 2;
    unsigned short* wprojB = (unsigned short*)p; p += (size_t)NCLS * HID * 2;
    int* bar = (int*)p;                         p += (size_t)32 * 4096 * 4;      // 512 KB flags

    // allow large dynamic LDS for the persistent kernel (w 96K + sg 3K + h 32K)
    hipFuncSetAttribute((const void*)gru_chunk,
                        hipFuncAttributeMaxDynamicSharedMemorySize, 134144);
    const int GRU_LDS = 134144;

    // ---- flag regions: reset every call (graph-replay safe) ----
    hipMemsetAsync(bar, 0, (size_t)32 * 4096 * 4, stream);

    // ---- one-time weight conversions ----
    conv_bf16<<<(NCLS * EMB) / 1024, 256, 0, stream>>>(emb, embB, NCLS * EMB);
    conv_bf16<<<(GATES * EMB) / 1024, 256, 0, stream>>>(w_ih0, wih0B, GATES * EMB);
    conv_bf16<<<(GATES * HID) / 1024, 256, 0, stream>>>(w_hh0, whh0B, GATES * HID);
    conv_bf16<<<(GATES * HID) / 1024, 256, 0, stream>>>(w_ih1, wih1B, GATES * HID);
    conv_bf16<<<(GATES * HID) / 1024, 256, 0, stream>>>(w_hh1, whh1B, GATES * HID);
    conv_bf16<<<(NCLS * HID) / 1024, 256, 0, stream>>>(w_proj, wprojB, NCLS * HID);

    // ---- init hidden state ----
    hipMemcpyAsync(h0f, hs, 65536 * 4, hipMemcpyDeviceToDevice, stream);
    hipMemcpyAsync(h1f, hs + 65536, 65536 * 4, hipMemcpyDeviceToDevice, stream);
    conv_bf16<<<64, 256, 0, stream>>>(hs, h0b0, 65536);
    conv_bf16<<<64, 256, 0, stream>>>(hs + 65536, h1b0, 65536);

    dim3 gg(ROWS / 64, GATES / 64);   // (16, 48)
    dim3 gp(ROWS / 64, NCLS / 64);    // (16, 2)

    for (int c = 0; c < SEQ / TCH; ++c) {
        int row_base = c * ROWS;

        // gi = embed[x] @ w_ih0^T + b_ih0 (gathered A)
        gemm_mfma<1><<<gg, 256, 0, stream>>>(nullptr, wih0B, b_ih0, gi, GATES, EMB, x, embB, row_base);

        // layer 0: 16 steps, one persistent launch
        gru_chunk<<<256, 256, GRU_LDS, stream>>>(gi, whh0B, b_hh0, h0f, h0b0, h0b1,
                                                 out0b, bar + (size_t)(c * 2 + 0) * 4096);

        // gi = out0 @ w_ih1^T + b_ih1
        gemm_mfma<0><<<gg, 256, 0, stream>>>(out0b, wih1B, b_ih1, gi, GATES, HID, nullptr, nullptr, 0);

        // layer 1: 16 steps, one persistent launch
        gru_chunk<<<256, 256, GRU_LDS, stream>>>(gi, whh1B, b_hh1, h1f, h1b0, h1b1,
                                                 out1b, bar + (size_t)(c * 2 + 1) * 4096);

        // logits chunk = out1 @ w_proj^T + b_proj (remapped store)
        gemm_mfma<2><<<gp, 256, 0, stream>>>(out1b, wprojB, b_proj, logits, NCLS, HID, nullptr, nullptr, row_base);
    }

    hipMemcpyAsync(hT, h0f, 65536 * 4, hipMemcpyDeviceToDevice, stream);
    hipMemcpyAsync(hT + 65536, h1f, 65536 * 4, hipMemcpyDeviceToDevice, stream);
}

// Round 8
// 3277.988 us; speedup vs baseline: 6.4948x; 1.0880x over previous
//
#include <hip/hip_runtime.h>
#include <hip/hip_bf16.h>

#define SEQ    256
#define BATCH  64
#define EMB    256
#define HID    1024
#define GATES  3072   // 3*HID
#define NCLS   128
#define TCH    16                 // time chunk
#define ROWS   (TCH * BATCH)      // 1024 rows per chunk
#define NCH    (SEQ / TCH)        // 16 chunks
#define MX     (ROWS / 64)        // 16 m-tiles per GEMM

#define HOFF   101376             // LDS byte offset of h tile (96K w + 3K sg)

typedef __attribute__((ext_vector_type(8))) short bf16x8;
typedef __attribute__((ext_vector_type(4))) float f32x4;

__device__ inline unsigned short f2bf(float x) {
    union { float f; unsigned int u; } v; v.f = x;
    v.u += 0x7fffu + ((v.u >> 16) & 1u);   // RNE
    return (unsigned short)(v.u >> 16);
}

// ---------------------------------------------------------------------------
// One-shot conversion of all weights (f32->bf16) + h-state init.
// Segments (element prefix sums): emb 32768 | wih0 819200 | whh0 3964928 |
// wih1 7110656 | whh1 10256384 | wproj 10387456 | hs 10518528.
// grid = 10518528/1024 = 10272 blocks x 256 thr, 4 elems/thread.
// ---------------------------------------------------------------------------
__global__ void conv_all(const float* __restrict__ emb, const float* __restrict__ wih0,
                         const float* __restrict__ whh0, const float* __restrict__ wih1,
                         const float* __restrict__ whh1, const float* __restrict__ wproj,
                         const float* __restrict__ hs,
                         unsigned short* __restrict__ embB, unsigned short* __restrict__ wih0B,
                         unsigned short* __restrict__ whh0B, unsigned short* __restrict__ wih1B,
                         unsigned short* __restrict__ whh1B, unsigned short* __restrict__ wprojB,
                         unsigned short* __restrict__ h0b0, unsigned short* __restrict__ h1b0,
                         float* __restrict__ h0f, float* __restrict__ h1f) {
    int i = (blockIdx.x * 256 + threadIdx.x) * 4;
    const float* src; unsigned short* dst; int off;
    if (i < 32768)         { src = emb;   dst = embB;   off = 0; }
    else if (i < 819200)   { src = wih0;  dst = wih0B;  off = 32768; }
    else if (i < 3964928)  { src = whh0;  dst = whh0B;  off = 819200; }
    else if (i < 7110656)  { src = wih1;  dst = wih1B;  off = 3964928; }
    else if (i < 10256384) { src = whh1;  dst = whh1B;  off = 7110656; }
    else if (i < 10387456) { src = wproj; dst = wprojB; off = 10256384; }
    else                   { src = hs;    dst = nullptr; off = 10387456; }
    int k = i - off;
    float4 v = *(const float4*)(src + k);
    if (dst) {
        dst[k + 0] = f2bf(v.x); dst[k + 1] = f2bf(v.y);
        dst[k + 2] = f2bf(v.z); dst[k + 3] = f2bf(v.w);
    } else {  // hs: bf16 ping buffer + f32 state (quads never straddle 65536)
        unsigned short* hb = (k < 65536) ? h0b0 + k : h1b0 + (k - 65536);
        float*          hf = (k < 65536) ? h0f + k  : h1f + (k - 65536);
        hb[0] = f2bf(v.x); hb[1] = f2bf(v.y); hb[2] = f2bf(v.z); hb[3] = f2bf(v.w);
        hf[0] = v.x; hf[1] = v.y; hf[2] = v.z; hf[3] = v.w;
    }
}

// ---------------------------------------------------------------------------
// bf16 MFMA GEMM device body: C[M,N] = A[M,K]*Bw[N,K]^T + bias[N]
// MODE 0 dense->rowmajor, 1 gathered-embedding A, 2 dense->remapped logits
// ---------------------------------------------------------------------------
template <int MODE>
__device__ __forceinline__ void gemm_dev(const unsigned short* __restrict__ A,
                                         const unsigned short* __restrict__ Bw,
                                         const float* __restrict__ bias,
                                         float* __restrict__ Cout, int N, int K,
                                         const int* __restrict__ xidx,
                                         const unsigned short* __restrict__ emb,
                                         int row_base, int bx, int by) {
    const int tid = threadIdx.x;
    const int w = tid >> 6, l = tid & 63;
    const int m0 = bx * 64 + w * 16;
    const int n0 = by * 64;
    const int la = l & 15, lk = (l >> 4) * 8;

    const unsigned short* arow;
    if (MODE == 1) {
        int g = row_base + m0 + la;
        int s = g >> 6, b = g & 63;
        arow = emb + (size_t)xidx[b * SEQ + s] * K + lk;
    } else {
        arow = A + (size_t)(m0 + la) * K + lk;
    }
    const unsigned short* brow = Bw + (size_t)(n0 + la) * K + lk;

    f32x4 acc[4] = {};
#pragma unroll 2
    for (int k = 0; k < K; k += 32) {
        bf16x8 a = *(const bf16x8*)(arow + k);
#pragma unroll
        for (int nt = 0; nt < 4; ++nt) {
            bf16x8 bb = *(const bf16x8*)(brow + (size_t)nt * 16 * K + k);
            acc[nt] = __builtin_amdgcn_mfma_f32_16x16x32_bf16(a, bb, acc[nt], 0, 0, 0);
        }
    }

    const int rbase = (l >> 4) * 4;
#pragma unroll
    for (int nt = 0; nt < 4; ++nt) {
        int colg = n0 + nt * 16 + la;
        float bsv = bias[colg];
#pragma unroll
        for (int i = 0; i < 4; ++i) {
            int rowg = m0 + rbase + i;
            float v = acc[nt][i] + bsv;
            if (MODE == 2) {
                int g = row_base + rowg;
                int s = g >> 6, b = g & 63;
                Cout[((size_t)(b * SEQ + s)) * NCLS + colg] = v;
            } else {
                Cout[(size_t)rowg * N + colg] = v;
            }
        }
    }
}

// ---------------------------------------------------------------------------
// Merged GEMM launch: blocks [0,na) gi0-gather, [na,na+nb) gi1, rest proj.
// ---------------------------------------------------------------------------
__global__ void gemm_multi(int na, int nb,
                           const int* __restrict__ x, const unsigned short* __restrict__ embB,
                           const unsigned short* __restrict__ wih0B, const float* __restrict__ bih0,
                           float* __restrict__ giA, int rbA,
                           const unsigned short* __restrict__ out0b,
                           const unsigned short* __restrict__ wih1B, const float* __restrict__ bih1,
                           float* __restrict__ giB,
                           const unsigned short* __restrict__ out1b,
                           const unsigned short* __restrict__ wprojB, const float* __restrict__ bproj,
                           float* __restrict__ logits, int rbP) {
    int bid = blockIdx.x;
    if (bid < na) {
        gemm_dev<1>(nullptr, wih0B, bih0, giA, GATES, EMB, x, embB, rbA, bid % MX, bid / MX);
    } else if (bid < na + nb) {
        int b = bid - na;
        gemm_dev<0>(out0b, wih1B, bih1, giB, GATES, HID, nullptr, nullptr, 0, b % MX, b / MX);
    } else {
        int b = bid - na - nb;
        gemm_dev<2>(out1b, wprojB, bproj, logits, NCLS, HID, nullptr, nullptr, rbP, b % MX, b / MX);
    }
}

// ---------------------------------------------------------------------------
// Persistent GRU chunk kernel (round-7 structure + gi prefetch at step top).
// ---------------------------------------------------------------------------
__global__ __launch_bounds__(256, 1)
void gru_chunk(const float* __restrict__ gi,
               const unsigned short* __restrict__ whb,   // [3072][1024] bf16
               const float* __restrict__ b_hh,
               float* __restrict__ h_f,                  // [64][1024] f32 persistent
               unsigned short* __restrict__ hb0,         // ping (entry state)
               unsigned short* __restrict__ hb1,         // pong
               unsigned short* __restrict__ outseq,      // [TCH*64][1024] bf16
               int* __restrict__ bar) {                  // this launch's flag region
    extern __shared__ char smem[];
    float* sg = (float*)(smem + 3 * 16 * HID * 2);            // 3*256 f32 @ 96K

    const int bg = blockIdx.x >> 6;
    const int jt = blockIdx.x & 63;
    const int b0 = bg * 16, j0 = jt * 16;
    const int tid = threadIdx.x;
    const int w = tid >> 6, l = tid & 63;

    // ---- stage w slice into LDS (once), swizzled: byte ^= (row&7)<<4 ----
#pragma unroll
    for (int c = 0; c < 24; ++c) {
        int u = tid + 256 * c;            // 16B-unit id, 0..6143
        int row = u >> 7;                 // 0..47  (g*16 + r)
        int off16 = u & 127;              // 16B offset within row
        int g = row >> 4, r = row & 15;
        const unsigned short* src = whb + (size_t)(g * HID + j0 + r) * HID + off16 * 8;
        int byte = row * 2048 + ((off16 * 16) ^ ((r & 7) << 4));
        *(bf16x8*)(smem + byte) = *(const bf16x8*)src;
    }

    // ---- own f32 state + biases ----
    const int prow = tid >> 4, pcol = tid & 15;
    const int pb = b0 + prow, pj = j0 + pcol;
    float hp = h_f[(size_t)pb * HID + pj];
    const float bhr = b_hh[pj], bhz = b_hh[HID + pj], bhn = b_hh[2 * HID + pj];

    __syncthreads();

    const unsigned short* hbuf[2] = {hb0, hb1};
    const int thi = tid >> 7;           // 0/1: which of the pair of rows
    const int tlo = tid & 127;          // 16B-unit within row

    for (int t = 0; t < TCH; ++t) {
        const unsigned short* hin = hbuf[t & 1];
        unsigned short* hout = (unsigned short*)hbuf[(t + 1) & 1];

        // ---- prefetch this step's gi operands (independent of h) ----
        const float* git = gi + ((size_t)(t * BATCH + pb)) * GATES;
        float gir = git[pj];
        float giz = git[HID + pj];
        float gin = git[2 * HID + pj];

        // ---- cooperative h-tile stage: 16 rows x 1024 bf16 = 32 KB ----
        bf16x8 h0v, h1v, h2v, h3v, h4v, h5v, h6v, h7v;
        {
            const unsigned short* s0 = hin + (size_t)(b0 + 0 + thi) * HID + tlo * 8;
            const unsigned short* s1 = hin + (size_t)(b0 + 2 + thi) * HID + tlo * 8;
            const unsigned short* s2 = hin + (size_t)(b0 + 4 + thi) * HID + tlo * 8;
            const unsigned short* s3 = hin + (size_t)(b0 + 6 + thi) * HID + tlo * 8;
            const unsigned short* s4 = hin + (size_t)(b0 + 8 + thi) * HID + tlo * 8;
            const unsigned short* s5 = hin + (size_t)(b0 + 10 + thi) * HID + tlo * 8;
            const unsigned short* s6 = hin + (size_t)(b0 + 12 + thi) * HID + tlo * 8;
            const unsigned short* s7 = hin + (size_t)(b0 + 14 + thi) * HID + tlo * 8;
            asm volatile(
                "global_load_dwordx4 %0, %8, off sc0 sc1\n\t"
                "global_load_dwordx4 %1, %9, off sc0 sc1\n\t"
                "global_load_dwordx4 %2, %10, off sc0 sc1\n\t"
                "global_load_dwordx4 %3, %11, off sc0 sc1\n\t"
                "global_load_dwordx4 %4, %12, off sc0 sc1\n\t"
                "global_load_dwordx4 %5, %13, off sc0 sc1\n\t"
                "global_load_dwordx4 %6, %14, off sc0 sc1\n\t"
                "global_load_dwordx4 %7, %15, off sc0 sc1"
                : "=&v"(h0v), "=&v"(h1v), "=&v"(h2v), "=&v"(h3v),
                  "=&v"(h4v), "=&v"(h5v), "=&v"(h6v), "=&v"(h7v)
                : "v"(s0), "v"(s1), "v"(s2), "v"(s3),
                  "v"(s4), "v"(s5), "v"(s6), "v"(s7));
            asm volatile("s_waitcnt vmcnt(0)" ::: "memory");
            __builtin_amdgcn_sched_barrier(0);
        }
#define HDST(c) (bf16x8*)(smem + HOFF + (2 * (c) + thi) * 2048 + \
                          ((tlo * 16) ^ (((2 * (c) + thi) & 7) << 4)))
        *HDST(0) = h0v; *HDST(1) = h1v; *HDST(2) = h2v; *HDST(3) = h3v;
        *HDST(4) = h4v; *HDST(5) = h5v; *HDST(6) = h6v; *HDST(7) = h7v;
#undef HDST
        __syncthreads();

        if (w < 3) {
            const int r = l & 15;
            const int sw = (r & 7) << 4;
            const int kq = (l >> 4) * 16;
            const int hbyte = HOFF + r * 2048;
            const int rowbyte = (w * 16 + r) * 2048;
            f32x4 acc = {};
#pragma unroll
            for (int ks = 0; ks < 32; ++ks) {
                bf16x8 a = *(const bf16x8*)(smem + hbyte + ((ks * 64 + kq) ^ sw));
                bf16x8 b = *(const bf16x8*)(smem + rowbyte + ((ks * 64 + kq) ^ sw));
                acc = __builtin_amdgcn_mfma_f32_16x16x32_bf16(a, b, acc, 0, 0, 0);
            }
            const int col = l & 15, rbase = (l >> 4) * 4;
#pragma unroll
            for (int i = 0; i < 4; ++i) sg[w * 256 + (rbase + i) * 16 + col] = acc[i];
        }
        __syncthreads();

        // ---- pointwise (all 256 threads, own (b,j)) ----
        float ghr = sg[0 * 256 + tid] + bhr;
        float ghz = sg[1 * 256 + tid] + bhz;
        float ghn = sg[2 * 256 + tid] + bhn;
        float rr = 1.f / (1.f + __expf(-(gir + ghr)));
        float zz = 1.f / (1.f + __expf(-(giz + ghz)));
        float nn = tanhf(gin + rr * ghn);
        hp = (1.f - zz) * nn + zz * hp;
        unsigned short hb = f2bf(hp);
        outseq[((size_t)(t * BATCH + pb)) * HID + pj] = hb;

        // coherence-point store of own h + per-wave drain
        asm volatile(
            "global_store_short %0, %1, off sc0 sc1\n\t"
            "s_waitcnt vmcnt(0)"
            :: "v"(hout + (size_t)pb * HID + pj), "v"((unsigned int)hb)
            : "memory");

        if (t < TCH - 1) {
            // ---- distributed-flag barrier over the 64 blocks of group bg ----
            __syncthreads();
            if (tid == 0) {
                __hip_atomic_store(bar + (((bg << 6) | jt) << 4), t + 1,
                                   __ATOMIC_RELAXED, __HIP_MEMORY_SCOPE_AGENT);
            }
            if (tid < 64) {
                const int* f = bar + (((bg << 6) | tid) << 4);
                while (!__all(__hip_atomic_load(f, __ATOMIC_RELAXED,
                                                __HIP_MEMORY_SCOPE_AGENT) > t)) {
                    __builtin_amdgcn_s_sleep(1);
                }
            }
            __syncthreads();
        }
    }

    h_f[(size_t)pb * HID + pj] = hp;
}

// ---------------------------------------------------------------------------
extern "C" void kernel_launch(void* const* d_in, const int* in_sizes, int n_in,
                              void* d_out, int out_size, void* d_ws, size_t ws_size,
                              hipStream_t stream) {
    const int*   x      = (const int*)d_in[0];
    const float* hs     = (const float*)d_in[1];
    const float* emb    = (const float*)d_in[2];
    const float* w_ih0  = (const float*)d_in[3];
    const float* w_hh0  = (const float*)d_in[4];
    const float* b_ih0  = (const float*)d_in[5];
    const float* b_hh0  = (const float*)d_in[6];
    const float* w_ih1  = (const float*)d_in[7];
    const float* w_hh1  = (const float*)d_in[8];
    const float* b_ih1  = (const float*)d_in[9];
    const float* b_hh1  = (const float*)d_in[10];
    const float* w_proj = (const float*)d_in[11];
    const float* b_proj = (const float*)d_in[12];

    float* logits = (float*)d_out;                       // [B*S, 128] f32
    float* hT     = logits + (size_t)SEQ * BATCH * NCLS; // [2, 64, 1024] f32

    // ---- workspace layout (~54 MB) ----
    char* p = (char*)d_ws;
    float* giA = (float*)p;                     p += (size_t)ROWS * GATES * 4;   // 12.6 MB
    float* giB = (float*)p;                     p += (size_t)ROWS * GATES * 4;   // 12.6 MB
    float* h0f = (float*)p;                     p += 65536 * 4;
    float* h1f = (float*)p;                     p += 65536 * 4;
    unsigned short* h0b0 = (unsigned short*)p;  p += 65536 * 2;
    unsigned short* h0b1 = (unsigned short*)p;  p += 65536 * 2;
    unsigned short* h1b0 = (unsigned short*)p;  p += 65536 * 2;
    unsigned short* h1b1 = (unsigned short*)p;  p += 65536 * 2;
    unsigned short* out0b = (unsigned short*)p; p += (size_t)ROWS * HID * 2;     // 2.1 MB
    unsigned short* out1b[2];
    out1b[0] = (unsigned short*)p;              p += (size_t)ROWS * HID * 2;     // 2.1 MB
    out1b[1] = (unsigned short*)p;              p += (size_t)ROWS * HID * 2;     // 2.1 MB
    unsigned short* embB  = (unsigned short*)p; p += (size_t)NCLS * EMB * 2;
    unsigned short* wih0B = (unsigned short*)p; p += (size_t)GATES * EMB * 2;
    unsigned short* whh0B = (unsigned short*)p; p += (size_t)GATES * HID * 2;
    unsigned short* wih1B = (unsigned short*)p; p += (size_t)GATES * HID * 2;
    unsigned short* whh1B = (unsigned short*)p; p += (size_t)GATES * HID * 2;
    unsigned short* wprojB = (unsigned short*)p; p += (size_t)NCLS * HID * 2;
    int* bar = (int*)p;                         p += (size_t)32 * 4096 * 4;      // 512 KB flags

    hipFuncSetAttribute((const void*)gru_chunk,
                        hipFuncAttributeMaxDynamicSharedMemorySize, 134144);
    const int GRU_LDS = 134144;

    // ---- flag regions: reset every call (graph-replay safe) ----
    hipMemsetAsync(bar, 0, (size_t)32 * 4096 * 4, stream);

    // ---- one launch: all weight conversions + h-state init ----
    conv_all<<<10272, 256, 0, stream>>>(emb, w_ih0, w_hh0, w_ih1, w_hh1, w_proj, hs,
                                        embB, wih0B, whh0B, wih1B, whh1B, wprojB,
                                        h0b0, h1b0, h0f, h1f);

    // ---- software-pipelined chunk loop: 3 launches per chunk ----
    for (int c = 0; c < NCH; ++c) {
        int na = 768;
        int nb = (c >= 1) ? 768 : 0;
        int np = (c >= 2) ? 32 : 0;
        gemm_multi<<<na + nb + np, 256, 0, stream>>>(na, nb,
            x, embB, wih0B, b_ih0, giA, c * ROWS,
            out0b, wih1B, b_ih1, giB,
            out1b[(c - 2) & 1], wprojB, b_proj, logits, (c >= 2) ? (c - 2) * ROWS : 0);

        if (c >= 1)
            gru_chunk<<<256, 256, GRU_LDS, stream>>>(giB, whh1B, b_hh1, h1f, h1b0, h1b1,
                                                     out1b[(c - 1) & 1],
                                                     bar + (size_t)(16 + c - 1) * 4096);

        gru_chunk<<<256, 256, GRU_LDS, stream>>>(giA, whh0B, b_hh0, h0f, h0b0, h0b1,
                                                 out0b, bar + (size_t)c * 4096);
    }

    // ---- pipeline tail: gi1(15)+proj(14), gru1(15), proj(15) ----
    gemm_multi<<<768 + 32, 256, 0, stream>>>(0, 768,
        x, embB, wih0B, b_ih0, giA, 0,
        out0b, wih1B, b_ih1, giB,
        out1b[0], wprojB, b_proj, logits, 14 * ROWS);

    gru_chunk<<<256, 256, GRU_LDS, stream>>>(giB, whh1B, b_hh1, h1f, h1b0, h1b1,
                                             out1b[1], bar + (size_t)(16 + 15) * 4096);

    gemm_multi<<<32, 256, 0, stream>>>(0, 0,
        x, embB, wih0B, b_ih0, giA, 0,
        out0b, wih1B, b_ih1, giB,
        out1b[1], wprojB, b_proj, logits, 15 * ROWS);

    hipMemcpyAsync(hT, h0f, 65536 * 4, hipMemcpyDeviceToDevice, stream);
    hipMemcpyAsync(hT + 65536, h1f, 65536 * 4, hipMemcpyDeviceToDevice, stream);
}

// Round 9
// 2268.390 us; speedup vs baseline: 9.3855x; 1.4451x over previous
//
#include <hip/hip_runtime.h>
#include <hip/hip_bf16.h>

#define SEQ    256
#define BATCH  64
#define EMB    256
#define HID    1024
#define GATES  3072   // 3*HID
#define NCLS   128
#define TCH    16                 // time chunk
#define ROWS   (TCH * BATCH)      // 1024 rows per chunk
#define NCH    (SEQ / TCH)        // 16 chunks
#define MX     (ROWS / 64)        // 16 m-tiles per GEMM

#define HOFF   101376             // LDS byte offset of h tile (96K w + 3K sg)

typedef __attribute__((ext_vector_type(8))) short bf16x8;
typedef __attribute__((ext_vector_type(4))) float f32x4;

__device__ inline unsigned short f2bf(float x) {
    union { float f; unsigned int u; } v; v.f = x;
    v.u += 0x7fffu + ((v.u >> 16) & 1u);   // RNE
    return (unsigned short)(v.u >> 16);
}

// ---------------------------------------------------------------------------
// One-shot conversion of all weights (f32->bf16) + h-state init.
// ---------------------------------------------------------------------------
__global__ void conv_all(const float* __restrict__ emb, const float* __restrict__ wih0,
                         const float* __restrict__ whh0, const float* __restrict__ wih1,
                         const float* __restrict__ whh1, const float* __restrict__ wproj,
                         const float* __restrict__ hs,
                         unsigned short* __restrict__ embB, unsigned short* __restrict__ wih0B,
                         unsigned short* __restrict__ whh0B, unsigned short* __restrict__ wih1B,
                         unsigned short* __restrict__ whh1B, unsigned short* __restrict__ wprojB,
                         unsigned short* __restrict__ h0b0, unsigned short* __restrict__ h1b0,
                         float* __restrict__ h0f, float* __restrict__ h1f) {
    int i = (blockIdx.x * 256 + threadIdx.x) * 4;
    const float* src; unsigned short* dst; int off;
    if (i < 32768)         { src = emb;   dst = embB;   off = 0; }
    else if (i < 819200)   { src = wih0;  dst = wih0B;  off = 32768; }
    else if (i < 3964928)  { src = whh0;  dst = whh0B;  off = 819200; }
    else if (i < 7110656)  { src = wih1;  dst = wih1B;  off = 3964928; }
    else if (i < 10256384) { src = whh1;  dst = whh1B;  off = 7110656; }
    else if (i < 10387456) { src = wproj; dst = wprojB; off = 10256384; }
    else                   { src = hs;    dst = nullptr; off = 10387456; }
    int k = i - off;
    float4 v = *(const float4*)(src + k);
    if (dst) {
        dst[k + 0] = f2bf(v.x); dst[k + 1] = f2bf(v.y);
        dst[k + 2] = f2bf(v.z); dst[k + 3] = f2bf(v.w);
    } else {
        unsigned short* hb = (k < 65536) ? h0b0 + k : h1b0 + (k - 65536);
        float*          hf = (k < 65536) ? h0f + k  : h1f + (k - 65536);
        hb[0] = f2bf(v.x); hb[1] = f2bf(v.y); hb[2] = f2bf(v.z); hb[3] = f2bf(v.w);
        hf[0] = v.x; hf[1] = v.y; hf[2] = v.z; hf[3] = v.w;
    }
}

// ---------------------------------------------------------------------------
// LDS-staged bf16 MFMA GEMM body: C[M,N] = A[M,K]*Bw[N,K]^T + bias[N]
// 64x64 tile, BK=128, 4 waves. Reg-staged cooperative loads (1 KB dense per
// wave-instr), XOR-swizzled LDS (slot = ku ^ (row&7)), prefetch of tile k+1
// issued between barriers so it hides under the MFMA/ds_read phase.
// MODE 0 dense->rowmajor, 1 gathered-embedding A, 2 dense->remapped logits
// LDS: A tile 16 KB @0, B tile 16 KB @8192 shorts.
// ---------------------------------------------------------------------------
template <int MODE, int KTOT>
__device__ __forceinline__ void gemm_dev(const unsigned short* __restrict__ A,
                                         const unsigned short* __restrict__ Bw,
                                         const float* __restrict__ bias,
                                         float* __restrict__ Cout, int N,
                                         const int* __restrict__ xidx,
                                         const unsigned short* __restrict__ emb,
                                         int row_base, int bx, int by,
                                         unsigned short* smem) {
    const int tid = threadIdx.x;
    const int w = tid >> 6, l = tid & 63;
    const int m0 = bx * 64, n0 = by * 64;
    const int r = l & 15;

    // ---- staging geometry: 4 A-units + 4 B-units per thread, 16 B each ----
    const unsigned short* apt[4];
    const unsigned short* bpt[4];
    int wrA[4], wrB[4];
#pragma unroll
    for (int i = 0; i < 4; ++i) {
        int u = tid + 256 * i;        // 0..1023
        int row = u >> 4;             // 0..63
        int ku = u & 15;              // 16B-unit within 256B row
        int slot = ku ^ (row & 7);
        if (MODE == 1) {
            int g = row_base + m0 + row;
            apt[i] = emb + (size_t)xidx[(g & 63) * SEQ + (g >> 6)] * KTOT + ku * 8;
        } else {
            apt[i] = A + (size_t)(m0 + row) * KTOT + ku * 8;
        }
        bpt[i] = Bw + (size_t)(n0 + row) * KTOT + ku * 8;
        wrA[i] = row * 128 + slot * 8;           // shorts
        wrB[i] = 8192 + row * 128 + slot * 8;
    }

    f32x4 acc[4] = {};
    bf16x8 va[4], vb[4];

#pragma unroll
    for (int i = 0; i < 4; ++i) va[i] = *(const bf16x8*)(apt[i]);
#pragma unroll
    for (int i = 0; i < 4; ++i) vb[i] = *(const bf16x8*)(bpt[i]);

    constexpr int NKB = KTOT / 128;
#pragma unroll
    for (int kb = 0; kb < NKB; ++kb) {
        // regs -> LDS
#pragma unroll
        for (int i = 0; i < 4; ++i) *(bf16x8*)(smem + wrA[i]) = va[i];
#pragma unroll
        for (int i = 0; i < 4; ++i) *(bf16x8*)(smem + wrB[i]) = vb[i];
        __syncthreads();
        // issue next tile's global loads (latency hides under compute below)
        if (kb + 1 < NKB) {
            const int ko = (kb + 1) * 128;
#pragma unroll
            for (int i = 0; i < 4; ++i) va[i] = *(const bf16x8*)(apt[i] + ko);
#pragma unroll
            for (int i = 0; i < 4; ++i) vb[i] = *(const bf16x8*)(bpt[i] + ko);
        }
        // compute from LDS
#pragma unroll
        for (int ks = 0; ks < 4; ++ks) {
            const int slot = (ks * 4 + (l >> 4)) ^ (r & 7);
            bf16x8 a = *(const bf16x8*)(smem + (w * 16 + r) * 128 + slot * 8);
#pragma unroll
            for (int nt = 0; nt < 4; ++nt) {
                bf16x8 b = *(const bf16x8*)(smem + 8192 + (nt * 16 + r) * 128 + slot * 8);
                acc[nt] = __builtin_amdgcn_mfma_f32_16x16x32_bf16(a, b, acc[nt], 0, 0, 0);
            }
        }
        __syncthreads();
    }

    // ---- epilogue (same C/D mapping as proven rounds 3-8) ----
    const int la = l & 15, rbase = (l >> 4) * 4;
#pragma unroll
    for (int nt = 0; nt < 4; ++nt) {
        int colg = n0 + nt * 16 + la;
        float bsv = bias[colg];
#pragma unroll
        for (int i = 0; i < 4; ++i) {
            int rowg = m0 + w * 16 + rbase + i;
            float v = acc[nt][i] + bsv;
            if (MODE == 2) {
                int g = row_base + rowg;
                int s = g >> 6, b = g & 63;
                Cout[((size_t)(b * SEQ + s)) * NCLS + colg] = v;
            } else {
                Cout[(size_t)rowg * N + colg] = v;
            }
        }
    }
}

// ---------------------------------------------------------------------------
// Merged GEMM launch: blocks [0,na) gi0-gather, [na,na+nb) gi1, rest proj.
// ---------------------------------------------------------------------------
__global__ __launch_bounds__(256)
void gemm_multi(int na, int nb,
                const int* __restrict__ x, const unsigned short* __restrict__ embB,
                const unsigned short* __restrict__ wih0B, const float* __restrict__ bih0,
                float* __restrict__ giA, int rbA,
                const unsigned short* __restrict__ out0b,
                const unsigned short* __restrict__ wih1B, const float* __restrict__ bih1,
                float* __restrict__ giB,
                const unsigned short* __restrict__ out1b,
                const unsigned short* __restrict__ wprojB, const float* __restrict__ bproj,
                float* __restrict__ logits, int rbP) {
    __shared__ unsigned short smem[16384];   // 32 KB
    int bid = blockIdx.x;
    if (bid < na) {
        gemm_dev<1, EMB>(nullptr, wih0B, bih0, giA, GATES, x, embB, rbA,
                         bid % MX, bid / MX, smem);
    } else if (bid < na + nb) {
        int b = bid - na;
        gemm_dev<0, HID>(out0b, wih1B, bih1, giB, GATES, nullptr, nullptr, 0,
                         b % MX, b / MX, smem);
    } else {
        int b = bid - na - nb;
        gemm_dev<2, HID>(out1b, wprojB, bproj, logits, NCLS, nullptr, nullptr, rbP,
                         b % MX, b / MX, smem);
    }
}

// ---------------------------------------------------------------------------
// Persistent GRU chunk kernel (round-7/8 structure, unchanged).
// ---------------------------------------------------------------------------
__global__ __launch_bounds__(256, 1)
void gru_chunk(const float* __restrict__ gi,
               const unsigned short* __restrict__ whb,   // [3072][1024] bf16
               const float* __restrict__ b_hh,
               float* __restrict__ h_f,                  // [64][1024] f32 persistent
               unsigned short* __restrict__ hb0,         // ping (entry state)
               unsigned short* __restrict__ hb1,         // pong
               unsigned short* __restrict__ outseq,      // [TCH*64][1024] bf16
               int* __restrict__ bar) {                  // this launch's flag region
    extern __shared__ char smem[];
    float* sg = (float*)(smem + 3 * 16 * HID * 2);            // 3*256 f32 @ 96K

    const int bg = blockIdx.x >> 6;
    const int jt = blockIdx.x & 63;
    const int b0 = bg * 16, j0 = jt * 16;
    const int tid = threadIdx.x;
    const int w = tid >> 6, l = tid & 63;

    // ---- stage w slice into LDS (once), swizzled: byte ^= (row&7)<<4 ----
#pragma unroll
    for (int c = 0; c < 24; ++c) {
        int u = tid + 256 * c;            // 16B-unit id, 0..6143
        int row = u >> 7;                 // 0..47  (g*16 + r)
        int off16 = u & 127;              // 16B offset within row
        int g = row >> 4, r = row & 15;
        const unsigned short* src = whb + (size_t)(g * HID + j0 + r) * HID + off16 * 8;
        int byte = row * 2048 + ((off16 * 16) ^ ((r & 7) << 4));
        *(bf16x8*)(smem + byte) = *(const bf16x8*)src;
    }

    // ---- own f32 state + biases ----
    const int prow = tid >> 4, pcol = tid & 15;
    const int pb = b0 + prow, pj = j0 + pcol;
    float hp = h_f[(size_t)pb * HID + pj];
    const float bhr = b_hh[pj], bhz = b_hh[HID + pj], bhn = b_hh[2 * HID + pj];

    __syncthreads();

    const unsigned short* hbuf[2] = {hb0, hb1};
    const int thi = tid >> 7;           // 0/1: which of the pair of rows
    const int tlo = tid & 127;          // 16B-unit within row

    for (int t = 0; t < TCH; ++t) {
        const unsigned short* hin = hbuf[t & 1];
        unsigned short* hout = (unsigned short*)hbuf[(t + 1) & 1];

        // ---- prefetch this step's gi operands (independent of h) ----
        const float* git = gi + ((size_t)(t * BATCH + pb)) * GATES;
        float gir = git[pj];
        float giz = git[HID + pj];
        float gin = git[2 * HID + pj];

        // ---- cooperative h-tile stage: 16 rows x 1024 bf16 = 32 KB ----
        bf16x8 h0v, h1v, h2v, h3v, h4v, h5v, h6v, h7v;
        {
            const unsigned short* s0 = hin + (size_t)(b0 + 0 + thi) * HID + tlo * 8;
            const unsigned short* s1 = hin + (size_t)(b0 + 2 + thi) * HID + tlo * 8;
            const unsigned short* s2 = hin + (size_t)(b0 + 4 + thi) * HID + tlo * 8;
            const unsigned short* s3 = hin + (size_t)(b0 + 6 + thi) * HID + tlo * 8;
            const unsigned short* s4 = hin + (size_t)(b0 + 8 + thi) * HID + tlo * 8;
            const unsigned short* s5 = hin + (size_t)(b0 + 10 + thi) * HID + tlo * 8;
            const unsigned short* s6 = hin + (size_t)(b0 + 12 + thi) * HID + tlo * 8;
            const unsigned short* s7 = hin + (size_t)(b0 + 14 + thi) * HID + tlo * 8;
            asm volatile(
                "global_load_dwordx4 %0, %8, off sc0 sc1\n\t"
                "global_load_dwordx4 %1, %9, off sc0 sc1\n\t"
                "global_load_dwordx4 %2, %10, off sc0 sc1\n\t"
                "global_load_dwordx4 %3, %11, off sc0 sc1\n\t"
                "global_load_dwordx4 %4, %12, off sc0 sc1\n\t"
                "global_load_dwordx4 %5, %13, off sc0 sc1\n\t"
                "global_load_dwordx4 %6, %14, off sc0 sc1\n\t"
                "global_load_dwordx4 %7, %15, off sc0 sc1"
                : "=&v"(h0v), "=&v"(h1v), "=&v"(h2v), "=&v"(h3v),
                  "=&v"(h4v), "=&v"(h5v), "=&v"(h6v), "=&v"(h7v)
                : "v"(s0), "v"(s1), "v"(s2), "v"(s3),
                  "v"(s4), "v"(s5), "v"(s6), "v"(s7));
            asm volatile("s_waitcnt vmcnt(0)" ::: "memory");
            __builtin_amdgcn_sched_barrier(0);
        }
#define HDST(c) (bf16x8*)(smem + HOFF + (2 * (c) + thi) * 2048 + \
                          ((tlo * 16) ^ (((2 * (c) + thi) & 7) << 4)))
        *HDST(0) = h0v; *HDST(1) = h1v; *HDST(2) = h2v; *HDST(3) = h3v;
        *HDST(4) = h4v; *HDST(5) = h5v; *HDST(6) = h6v; *HDST(7) = h7v;
#undef HDST
        __syncthreads();

        if (w < 3) {
            const int r = l & 15;
            const int sw = (r & 7) << 4;
            const int kq = (l >> 4) * 16;
            const int hbyte = HOFF + r * 2048;
            const int rowbyte = (w * 16 + r) * 2048;
            f32x4 acc = {};
#pragma unroll
            for (int ks = 0; ks < 32; ++ks) {
                bf16x8 a = *(const bf16x8*)(smem + hbyte + ((ks * 64 + kq) ^ sw));
                bf16x8 b = *(const bf16x8*)(smem + rowbyte + ((ks * 64 + kq) ^ sw));
                acc = __builtin_amdgcn_mfma_f32_16x16x32_bf16(a, b, acc, 0, 0, 0);
            }
            const int col = l & 15, rbase = (l >> 4) * 4;
#pragma unroll
            for (int i = 0; i < 4; ++i) sg[w * 256 + (rbase + i) * 16 + col] = acc[i];
        }
        __syncthreads();

        // ---- pointwise (all 256 threads, own (b,j)) ----
        float ghr = sg[0 * 256 + tid] + bhr;
        float ghz = sg[1 * 256 + tid] + bhz;
        float ghn = sg[2 * 256 + tid] + bhn;
        float rr = 1.f / (1.f + __expf(-(gir + ghr)));
        float zz = 1.f / (1.f + __expf(-(giz + ghz)));
        float nn = tanhf(gin + rr * ghn);
        hp = (1.f - zz) * nn + zz * hp;
        unsigned short hb = f2bf(hp);
        outseq[((size_t)(t * BATCH + pb)) * HID + pj] = hb;

        // coherence-point store of own h + per-wave drain
        asm volatile(
            "global_store_short %0, %1, off sc0 sc1\n\t"
            "s_waitcnt vmcnt(0)"
            :: "v"(hout + (size_t)pb * HID + pj), "v"((unsigned int)hb)
            : "memory");

        if (t < TCH - 1) {
            // ---- distributed-flag barrier over the 64 blocks of group bg ----
            __syncthreads();
            if (tid == 0) {
                __hip_atomic_store(bar + (((bg << 6) | jt) << 4), t + 1,
                                   __ATOMIC_RELAXED, __HIP_MEMORY_SCOPE_AGENT);
            }
            if (tid < 64) {
                const int* f = bar + (((bg << 6) | tid) << 4);
                while (!__all(__hip_atomic_load(f, __ATOMIC_RELAXED,
                                                __HIP_MEMORY_SCOPE_AGENT) > t)) {
                    __builtin_amdgcn_s_sleep(1);
                }
            }
            __syncthreads();
        }
    }

    h_f[(size_t)pb * HID + pj] = hp;
}

// ---------------------------------------------------------------------------
extern "C" void kernel_launch(void* const* d_in, const int* in_sizes, int n_in,
                              void* d_out, int out_size, void* d_ws, size_t ws_size,
                              hipStream_t stream) {
    const int*   x      = (const int*)d_in[0];
    const float* hs     = (const float*)d_in[1];
    const float* emb    = (const float*)d_in[2];
    const float* w_ih0  = (const float*)d_in[3];
    const float* w_hh0  = (const float*)d_in[4];
    const float* b_ih0  = (const float*)d_in[5];
    const float* b_hh0  = (const float*)d_in[6];
    const float* w_ih1  = (const float*)d_in[7];
    const float* w_hh1  = (const float*)d_in[8];
    const float* b_ih1  = (const float*)d_in[9];
    const float* b_hh1  = (const float*)d_in[10];
    const float* w_proj = (const float*)d_in[11];
    const float* b_proj = (const float*)d_in[12];

    float* logits = (float*)d_out;                       // [B*S, 128] f32
    float* hT     = logits + (size_t)SEQ * BATCH * NCLS; // [2, 64, 1024] f32

    // ---- workspace layout (~54 MB) ----
    char* p = (char*)d_ws;
    float* giA = (float*)p;                     p += (size_t)ROWS * GATES * 4;   // 12.6 MB
    float* giB = (float*)p;                     p += (size_t)ROWS * GATES * 4;   // 12.6 MB
    float* h0f = (float*)p;                     p += 65536 * 4;
    float* h1f = (float*)p;                     p += 65536 * 4;
    unsigned short* h0b0 = (unsigned short*)p;  p += 65536 * 2;
    unsigned short* h0b1 = (unsigned short*)p;  p += 65536 * 2;
    unsigned short* h1b0 = (unsigned short*)p;  p += 65536 * 2;
    unsigned short* h1b1 = (unsigned short*)p;  p += 65536 * 2;
    unsigned short* out0b = (unsigned short*)p; p += (size_t)ROWS * HID * 2;     // 2.1 MB
    unsigned short* out1b[2];
    out1b[0] = (unsigned short*)p;              p += (size_t)ROWS * HID * 2;     // 2.1 MB
    out1b[1] = (unsigned short*)p;              p += (size_t)ROWS * HID * 2;     // 2.1 MB
    unsigned short* embB  = (unsigned short*)p; p += (size_t)NCLS * EMB * 2;
    unsigned short* wih0B = (unsigned short*)p; p += (size_t)GATES * EMB * 2;
    unsigned short* whh0B = (unsigned short*)p; p += (size_t)GATES * HID * 2;
    unsigned short* wih1B = (unsigned short*)p; p += (size_t)GATES * HID * 2;
    unsigned short* whh1B = (unsigned short*)p; p += (size_t)GATES * HID * 2;
    unsigned short* wprojB = (unsigned short*)p; p += (size_t)NCLS * HID * 2;
    int* bar = (int*)p;                         p += (size_t)32 * 4096 * 4;      // 512 KB flags

    hipFuncSetAttribute((const void*)gru_chunk,
                        hipFuncAttributeMaxDynamicSharedMemorySize, 134144);
    const int GRU_LDS = 134144;

    // ---- flag regions: reset every call (graph-replay safe) ----
    hipMemsetAsync(bar, 0, (size_t)32 * 4096 * 4, stream);

    // ---- one launch: all weight conversions + h-state init ----
    conv_all<<<10272, 256, 0, stream>>>(emb, w_ih0, w_hh0, w_ih1, w_hh1, w_proj, hs,
                                        embB, wih0B, whh0B, wih1B, whh1B, wprojB,
                                        h0b0, h1b0, h0f, h1f);

    // ---- software-pipelined chunk loop: 3 launches per chunk ----
    for (int c = 0; c < NCH; ++c) {
        int na = 768;
        int nb = (c >= 1) ? 768 : 0;
        int np = (c >= 2) ? 32 : 0;
        gemm_multi<<<na + nb + np, 256, 0, stream>>>(na, nb,
            x, embB, wih0B, b_ih0, giA, c * ROWS,
            out0b, wih1B, b_ih1, giB,
            out1b[(c - 2) & 1], wprojB, b_proj, logits, (c >= 2) ? (c - 2) * ROWS : 0);

        if (c >= 1)
            gru_chunk<<<256, 256, GRU_LDS, stream>>>(giB, whh1B, b_hh1, h1f, h1b0, h1b1,
                                                     out1b[(c - 1) & 1],
                                                     bar + (size_t)(16 + c - 1) * 4096);

        gru_chunk<<<256, 256, GRU_LDS, stream>>>(giA, whh0B, b_hh0, h0f, h0b0, h0b1,
                                                 out0b, bar + (size_t)c * 4096);
    }

    // ---- pipeline tail: gi1(15)+proj(14), gru1(15), proj(15) ----
    gemm_multi<<<768 + 32, 256, 0, stream>>>(0, 768,
        x, embB, wih0B, b_ih0, giA, 0,
        out0b, wih1B, b_ih1, giB,
        out1b[0], wprojB, b_proj, logits, 14 * ROWS);

    gru_chunk<<<256, 256, GRU_LDS, stream>>>(giB, whh1B, b_hh1, h1f, h1b0, h1b1,
                                             out1b[1], bar + (size_t)(16 + 15) * 4096);

    gemm_multi<<<32, 256, 0, stream>>>(0, 0,
        x, embB, wih0B, b_ih0, giA, 0,
        out0b, wih1B, b_ih1, giB,
        out1b[1], wprojB, b_proj, logits, 15 * ROWS);

    hipMemcpyAsync(hT, h0f, 65536 * 4, hipMemcpyDeviceToDevice, stream);
    hipMemcpyAsync(hT + 65536, h1f, 65536 * 4, hipMemcpyDeviceToDevice, stream);
}